// Round 1
// baseline (196.262 us; speedup 1.0000x reference)
//
#include <hip/hip_runtime.h>
#include <stdint.h>

#define BROWS 16384
#define DDIM  512
#define EEXP  16
#define HDIM  256
#define LDIM  64
#define BM    64

typedef __bf16  bf16x8  __attribute__((ext_vector_type(8)));
typedef float   floatx4 __attribute__((ext_vector_type(4)));
typedef ushort  ushort8 __attribute__((ext_vector_type(8)));
typedef unsigned int u32;

__device__ __forceinline__ ushort f2bf(float f) {
    uint32_t u = __builtin_bit_cast(uint32_t, f);
    u += 0x7fffu + ((u >> 16) & 1u);   // RNE
    return (ushort)(u >> 16);
}

// tanh(x) = 1 - 2/(exp2(2x*log2e)+1); saturates correctly, rel err ~1e-6.
__device__ __forceinline__ float fast_tanh(float x) {
    float e = __builtin_amdgcn_exp2f(x * 2.8853900817779268f);
    return 1.0f - 2.0f * __builtin_amdgcn_rcpf(e + 1.0f);
}

__device__ __forceinline__ void gl_lds16(const void* g, void* l) {
    __builtin_amdgcn_global_load_lds(
        (const __attribute__((address_space(1))) u32*)g,
        (__attribute__((address_space(3))) u32*)l, 16, 0, 0);
}

// ---------------------------------------------------------------------------
// Gating (f32, math unchanged) + fused x f32->bf16 swizzled cvt
// + per-(expert, gating-block) row slots (NO global atomics -> sortable).
// 32 rows/block; thread = (rg 0..15, og 0..15): 2 rows x (wg,wn) each.
// ---------------------------------------------------------------------------
__global__ __launch_bounds__(256) void gating_kernel(
    const float* __restrict__ x,      // [B][D]
    const float* __restrict__ noise,  // [B][E]
    const float* __restrict__ wg,     // [D][E]
    const float* __restrict__ wn,     // [D][E]
    float* __restrict__ gates,        // [B][E]
    ushort* __restrict__ xbf,         // [B][D] bf16 swizzled
    u32* __restrict__ cntb,           // [E][512] per-block counts
    u32* __restrict__ rowtmp)         // [E][512*32] slotted rows
{
    __shared__ __align__(16) float xs[32 * 132];    // 16.5 KB
    __shared__ __align__(16) float wTg[16 * 132];   // 8.25 KB
    __shared__ __align__(16) float wTn[16 * 132];   // 8.25 KB
    __shared__ u32 lcnt[16];
    __shared__ ushort lrows[16 * 32];

    const int t    = threadIdx.x;
    const int blk  = blockIdx.x;
    const int row0 = blk * 32;
    const int og   = t & 15, rg = t >> 4;

    if (t < 16) lcnt[t] = 0;

    floatx4 accg4[2] = {}, accn4[2] = {};

    for (int ch = 0; ch < 4; ++ch) {
        const int k0 = ch * 128;
        __syncthreads();
        {   // stage xs[32][128] + fused bf16 swizzled writeback
            int r = t >> 3, c = (t & 7) * 16;
            const float* src = &x[(size_t)(row0 + r) * DDIM + k0 + c];
            float4 f[4];
            #pragma unroll
            for (int i = 0; i < 4; ++i)
                f[i] = reinterpret_cast<const float4*>(src)[i];
            float* dst = &xs[r * 132 + c];
            #pragma unroll
            for (int i = 0; i < 4; ++i)
                reinterpret_cast<float4*>(dst)[i] = f[i];

            const int row = row0 + r;
            const int sw  = r & 7;
            #pragma unroll
            for (int i = 0; i < 2; ++i) {
                int cb = k0 + c + i * 8;
                int kb = cb >> 6;
                int g  = (cb >> 3) & 7;
                int gp = g ^ sw;
                float4 a = f[i * 2], b = f[i * 2 + 1];
                ushort8 t8;
                t8[0]=f2bf(a.x); t8[1]=f2bf(a.y); t8[2]=f2bf(a.z); t8[3]=f2bf(a.w);
                t8[4]=f2bf(b.x); t8[5]=f2bf(b.y); t8[6]=f2bf(b.z); t8[7]=f2bf(b.w);
                *reinterpret_cast<ushort8*>(&xbf[(size_t)row * DDIM + kb * 64 + gp * 8]) = t8;
            }
        }
        {   // stage wTg/wTn transposed (pad 132 -> conflict-free reads)
            int d = t >> 1, e0 = (t & 1) * 8;
            float4 a0 = *reinterpret_cast<const float4*>(&wg[(size_t)(k0 + d) * EEXP + e0]);
            float4 a1 = *reinterpret_cast<const float4*>(&wg[(size_t)(k0 + d) * EEXP + e0 + 4]);
            float4 b0 = *reinterpret_cast<const float4*>(&wn[(size_t)(k0 + d) * EEXP + e0]);
            float4 b1 = *reinterpret_cast<const float4*>(&wn[(size_t)(k0 + d) * EEXP + e0 + 4]);
            wTg[(e0+0)*132+d]=a0.x; wTg[(e0+1)*132+d]=a0.y; wTg[(e0+2)*132+d]=a0.z; wTg[(e0+3)*132+d]=a0.w;
            wTg[(e0+4)*132+d]=a1.x; wTg[(e0+5)*132+d]=a1.y; wTg[(e0+6)*132+d]=a1.z; wTg[(e0+7)*132+d]=a1.w;
            wTn[(e0+0)*132+d]=b0.x; wTn[(e0+1)*132+d]=b0.y; wTn[(e0+2)*132+d]=b0.z; wTn[(e0+3)*132+d]=b0.w;
            wTn[(e0+4)*132+d]=b1.x; wTn[(e0+5)*132+d]=b1.y; wTn[(e0+6)*132+d]=b1.z; wTn[(e0+7)*132+d]=b1.w;
        }
        __syncthreads();

        #pragma unroll 8
        for (int d4 = 0; d4 < 32; ++d4) {
            floatx4 wgv = *reinterpret_cast<const floatx4*>(&wTg[og * 132 + d4 * 4]);
            floatx4 wnv = *reinterpret_cast<const floatx4*>(&wTn[og * 132 + d4 * 4]);
            #pragma unroll
            for (int rr = 0; rr < 2; ++rr) {
                floatx4 xv = *reinterpret_cast<const floatx4*>(&xs[(rg * 2 + rr) * 132 + d4 * 4]);
                accg4[rr] += xv * wgv;
                accn4[rr] += xv * wnv;
            }
        }
    }

    #pragma unroll
    for (int rr = 0; rr < 2; ++rr) {
        const int row = row0 + rg * 2 + rr;
        float accg = accg4[rr][0] + accg4[rr][1] + accg4[rr][2] + accg4[rr][3];
        float accn = accn4[rr][0] + accn4[rr][1] + accn4[rr][2] + accn4[rr][3];

        // keep libcall-precision softplus: gate threshold flips are the risk
        float sp = fmaxf(accn, 0.f) + log1pf(expf(-fabsf(accn)));
        float stddev = sp + 0.01f;
        float nz = noise[(size_t)row * EEXP + og];
        float z = accg + nz * stddev;

        float m = z;
        #pragma unroll
        for (int mask = 8; mask >= 1; mask >>= 1)
            m = fmaxf(m, __shfl_xor(m, mask, 16));
        float ez = expf(z - m);
        float s = ez;
        #pragma unroll
        for (int mask = 8; mask >= 1; mask >>= 1)
            s += __shfl_xor(s, mask, 16);
        float logit = ez / s;

        float lsum = logit;
        #pragma unroll
        for (int mask = 8; mask >= 1; mask >>= 1)
            lsum += __shfl_xor(lsum, mask, 16);
        float mean = lsum * (1.0f / 16.0f) - 1e-8f;

        float gate = (logit >= mean) ? logit : 0.0f;
        float denom = gate;
        #pragma unroll
        for (int mask = 8; mask >= 1; mask >>= 1)
            denom += __shfl_xor(denom, mask, 16);

        gates[(size_t)row * EEXP + og] = gate / denom;

        if (gate > 0.0f) {
            u32 p = atomicAdd(&lcnt[og], 1u);
            lrows[og * 32 + p] = (ushort)(rg * 2 + rr);
        }
    }

    __syncthreads();
    if (t < 16) cntb[t * 512 + blk] = lcnt[t];
    for (int i = t; i < 16 * 32; i += 256) {
        int e = i >> 5, j = i & 31;
        if ((u32)j < lcnt[e])
            rowtmp[(size_t)e * 16384 + blk * 32 + j] = row0 + lrows[e * 32 + j];
    }
}

// ---------------------------------------------------------------------------
// Compaction: block b (512 total) computes bases[e][b] = sum cntb[e][0..b)
// redundantly (wave-parallel, L2-hot), then copies its <=32 rows per expert
// into the globally SORTED rowlist. Block 511 also writes cnt[e].
// ---------------------------------------------------------------------------
__global__ __launch_bounds__(256) void compact_kernel(
    const u32* __restrict__ cntb,     // [E][512]
    const u32* __restrict__ rowtmp,   // [E][512*32]
    u32* __restrict__ rowlist,        // [E][B] sorted
    u32* __restrict__ cnt)            // [E]
{
    __shared__ u32 base_s[16];
    const int b    = blockIdx.x;
    const int lane = threadIdx.x & 63;
    const int wave = threadIdx.x >> 6;

    for (int e = wave; e < 16; e += 4) {
        u32 s = 0;
        for (int i = lane; i < b; i += 64) s += cntb[e * 512 + i];
        #pragma unroll
        for (int off = 32; off; off >>= 1) s += __shfl_down(s, off, 64);
        if (lane == 0) {
            base_s[e] = s;
            if (b == 511) cnt[e] = s + cntb[e * 512 + 511];
        }
    }
    __syncthreads();

    const int t = threadIdx.x;
    for (int i = t; i < 512; i += 256) {
        int e = i >> 5, j = i & 31;
        if ((u32)j < cntb[e * 512 + b])
            rowlist[(size_t)e * BROWS + base_s[e] + j] =
                rowtmp[(size_t)e * 16384 + b * 32 + j];
    }
}

// ---------------------------------------------------------------------------
// Merged aux kernel: W1/W2 transpose+cvt (blocks 0..2303, LINEAR layout now —
// expert kernel consumes W1T straight from L2, no LDS staging) and zero-fill
// of inactive out slots (blocks 2304..18687). Runs after gating (needs gates).
// ---------------------------------------------------------------------------
__global__ __launch_bounds__(256) void aux_kernel(
    const float* __restrict__ W1, ushort* __restrict__ W1T,
    const float* __restrict__ W2, ushort* __restrict__ W2T,
    const float* __restrict__ gates, float* __restrict__ out)
{
    int b = blockIdx.x;
    if (b >= 2304) {   // zero-fill: one float4 per thread
        int i = (b - 2304) * 256 + threadIdx.x;
        int slot = i >> 4;
        if (gates[slot] == 0.0f) {
            float4 z = {0.f, 0.f, 0.f, 0.f};
            reinterpret_cast<float4*>(out)[i] = z;
        }
        return;
    }
    __shared__ float tile[32][33];
    const float* src; ushort* dst; int R, C, c0, r0, ei;
    if (b < 2048) {
        ei = b >> 7; int rem = b & 127;
        c0 = (rem & 7) * 32; r0 = (rem >> 3) * 32;
        R = DDIM; C = HDIM;
        src = W1; dst = W1T;
    } else {
        b -= 2048;
        ei = b >> 4; int rem = b & 15;
        c0 = (rem & 1) * 32; r0 = (rem >> 1) * 32;
        R = HDIM; C = LDIM;
        src = W2; dst = W2T;
    }
    const int tx = threadIdx.x & 31, ty = threadIdx.x >> 5;
    const float* s = src + (size_t)ei * R * C;
    ushort* d = dst + (size_t)ei * R * C;

    #pragma unroll
    for (int i = 0; i < 4; ++i) {
        int rr = ty + i * 8;
        tile[rr][tx] = s[(size_t)(r0 + rr) * C + c0 + tx];
    }
    __syncthreads();
    #pragma unroll
    for (int i = 0; i < 4; ++i) {
        int cc = ty + i * 8;
        int h = c0 + cc;
        d[(size_t)h * R + r0 + tx] = f2bf(tile[tx][cc]);
    }
}

// ---------------------------------------------------------------------------
// Sparse expert MLP, BM=64. Pipelined K-loop:
//   - A tile (gathered rows) double-buffered in LDS, staged 1 K-step ahead
//     via global_load_lds -> barrier's vmcnt drain hits ~complete loads.
//   - B operand (W1T, L2-resident per-XCD) read DIRECT global->VGPR with a
//     one-phase-ahead software prefetch (it had zero LDS reuse: each staged
//     byte was read exactly once). Removes 32 KB LDS write+read per K-step
//     and one of the two barriers.
// LDS 32 KB (A dbuf 16 KB, h reuses [0,32K) after phase A).
// ---------------------------------------------------------------------------
__global__ __launch_bounds__(256, 3) void expert_kernel(
    const ushort* __restrict__ xbf,    // [B][D] bf16, swizzled
    const float*  __restrict__ gates,  // [B][E]
    const ushort* __restrict__ W1T,    // [E][H][D] bf16, LINEAR
    const float*  __restrict__ b1,     // [E][H]
    const ushort* __restrict__ W2T,    // [E][L][H] bf16, linear
    const float*  __restrict__ b2,     // [E][L]
    const u32*    __restrict__ cnt,    // [E]
    const u32*    __restrict__ rowlist,// [E][B] sorted
    float* __restrict__ out)           // [B][E][L]
{
    __shared__ __align__(16) ushort lds[16384];  // 32 KB

    const int bx = blockIdx.x;
    const int e  = bx & 15;
    const int t  = bx >> 4;

    const int count = (int)cnt[e];
    if (t * BM >= count) return;
    const int nrt = min(BM, count - t * BM);
    const u32* rl = rowlist + (size_t)e * BROWS + t * BM;

    const int tid  = threadIdx.x;
    const int lane = tid & 63;
    const int wave = tid >> 6;

    const int lr = lane & 15;
    const int q  = lane >> 4;
    const int kq = q * 8;
    const int rq = q * 4;
    const int la = lane >> 3, lb = lane & 7;  // staging lane split

    const char* xg = (const char*)xbf;
    const char* w1 = (const char*)W1T + (size_t)e * HDIM * 1024;

    // Per-lane gathered A-row bases + swizzle re-key terms
    size_t abase[2]; int sxr[2];
    #pragma unroll
    for (int p = 0; p < 2; ++p) {
        int r  = wave * 16 + p * 8 + la;
        int rc = min(r, nrt - 1);
        u32 ri = rl[rc];
        abase[p] = (size_t)ri * 1024;
        sxr[p]   = (la ^ (int)(ri & 7)) << 4;
    }

    // Per-thread B fragment base addrs: row = wave*64 + j*16 + lr, col byte q*16
    const char* bptr[4];
    #pragma unroll
    for (int j = 0; j < 4; ++j)
        bptr[j] = w1 + (size_t)(wave * 64 + j * 16 + lr) * 1024 + q * 16;

    floatx4 acc[4][4] = {};

    // prefetch B for phase 0 (kb=0, s=0)
    bf16x8 bnx[4];
    #pragma unroll
    for (int j = 0; j < 4; ++j)
        bnx[j] = *reinterpret_cast<const bf16x8*>(bptr[j]);

    // stage A tile kb=0 into buffer 0
    #pragma unroll
    for (int p = 0; p < 2; ++p) {
        int c = wave * 2 + p;
        gl_lds16(xg + abase[p] + ((lb << 4) ^ sxr[p]), &lds[c * 512]);
    }
    __syncthreads();

    #pragma unroll
    for (int kb = 0; kb < 8; ++kb) {
        const int cur = (kb & 1) << 12;     // 0 / 4096 (ushort index)
        if (kb < 7) {   // prefetch next A tile into the other buffer
            const int koff = (kb + 1) * 128;
            #pragma unroll
            for (int p = 0; p < 2; ++p) {
                int c = wave * 2 + p;
                gl_lds16(xg + abase[p] + koff + ((lb << 4) ^ sxr[p]),
                         &lds[(cur ^ 4096) + c * 512]);
            }
        }
        #pragma unroll
        for (int s = 0; s < 2; ++s) {
            bf16x8 bc[4];
            #pragma unroll
            for (int j = 0; j < 4; ++j) bc[j] = bnx[j];
            const int pn = kb * 2 + s + 1;   // prefetch B one phase ahead
            if (pn < 16) {
                const int off = (pn >> 1) * 128 + (pn & 1) * 64;
                #pragma unroll
                for (int j = 0; j < 4; ++j)
                    bnx[j] = *reinterpret_cast<const bf16x8*>(bptr[j] + off);
            }
            const int g = s * 4 + q;
            bf16x8 af[4];
            #pragma unroll
            for (int i = 0; i < 4; ++i) {
                int r = i * 16 + lr;
                af[i] = *reinterpret_cast<const bf16x8*>(
                    &lds[cur + r * 64 + ((g ^ (r & 7)) << 3)]);
            }
            #pragma unroll
            for (int i = 0; i < 4; ++i)
                #pragma unroll
                for (int j = 0; j < 4; ++j)
                    acc[i][j] = __builtin_amdgcn_mfma_f32_16x16x32_bf16(
                        af[i], bc[j], acc[i][j], 0, 0, 0);
        }
        __syncthreads();
    }

    // h = fast_tanh(acc + b1) -> bf16, swizzled [64][256] at lds[0..32K)
    float b1v[4];
    #pragma unroll
    for (int j = 0; j < 4; ++j)
        b1v[j] = b1[e * HDIM + wave * 64 + j * 16 + lr];

    #pragma unroll
    for (int i = 0; i < 4; ++i)
        #pragma unroll
        for (int j = 0; j < 4; ++j) {
            int c = wave * 64 + j * 16 + lr;
            int gg = c >> 3;
            #pragma unroll
            for (int rr = 0; rr < 4; ++rr) {
                int r = i * 16 + rq + rr;
                float v = fast_tanh(acc[i][j][rr] + b1v[j]);
                lds[r * 256 + (((gg & 24) | ((gg & 7) ^ (r & 7))) << 3) + (c & 7)] = f2bf(v);
            }
        }
    __syncthreads();

    // Phase B: y[64][64]; wave owns rows [wave*16,+16); W2 frags from global
    const ushort* w2 = W2T + (size_t)e * LDIM * HDIM;
    floatx4 acc2[4] = {};
    #pragma unroll
    for (int s = 0; s < 8; ++s) {
        int r = wave * 16 + lr;
        int g = s * 4 + q;
        bf16x8 af = *reinterpret_cast<const bf16x8*>(
            &lds[r * 256 + (((g & 24) | ((g & 7) ^ (r & 7))) << 3)]);
        #pragma unroll
        for (int j = 0; j < 4; ++j) {
            bf16x8 bfr = *reinterpret_cast<const bf16x8*>(
                &w2[(size_t)(j * 16 + lr) * HDIM + s * 32 + kq]);
            acc2[j] = __builtin_amdgcn_mfma_f32_16x16x32_bf16(af, bfr, acc2[j], 0, 0, 0);
        }
    }

    float b2v[4];
    #pragma unroll
    for (int j = 0; j < 4; ++j)
        b2v[j] = b2[e * LDIM + j * 16 + lr];

    #pragma unroll
    for (int rr = 0; rr < 4; ++rr) {
        int r  = wave * 16 + rq + rr;
        int rc = min(r, nrt - 1);
        u32 ri = rl[rc];
        float gsc = gates[(size_t)ri * EEXP + e];
        if (r < nrt) {
            #pragma unroll
            for (int j = 0; j < 4; ++j)
                out[(size_t)ri * (EEXP * LDIM) + e * LDIM + j * 16 + lr] =
                    (acc2[j][rr] + b2v[j]) * gsc;
        }
    }
}

// ---------------------------------------------------------------------------
extern "C" void kernel_launch(void* const* d_in, const int* in_sizes, int n_in,
                              void* d_out, int out_size, void* d_ws, size_t ws_size,
                              hipStream_t stream) {
    (void)in_sizes; (void)n_in; (void)out_size; (void)ws_size;
    const float* x     = (const float*)d_in[0];
    const float* noise = (const float*)d_in[1];
    const float* wg    = (const float*)d_in[2];
    const float* wn    = (const float*)d_in[3];
    const float* W1    = (const float*)d_in[4];
    const float* b1    = (const float*)d_in[5];
    const float* W2    = (const float*)d_in[6];
    const float* b2    = (const float*)d_in[7];
    float* out = (float*)d_out;

    char* ws = (char*)d_ws;
    float*  gates   = (float*)ws;                          // 1 MiB
    ushort* W1T     = (ushort*)(ws + (1 << 20));           // 4 MiB
    ushort* W2T     = (ushort*)(ws + (5 << 20));           // 0.5 MiB
    ushort* xbf     = (ushort*)(ws + (6 << 20));           // 16 MiB
    u32*    cntb    = (u32*)(ws + (22 << 20));             // 32 KiB
    u32*    cnt     = (u32*)(ws + (22 << 20) + (32 << 10));// 64 B
    u32*    rowtmp  = (u32*)(ws + (23 << 20));             // 1 MiB
    u32*    rowlist = (u32*)(ws + (24 << 20));             // 1 MiB

    gating_kernel<<<BROWS / 32, 256, 0, stream>>>(x, noise, wg, wn, gates, xbf, cntb, rowtmp);
    compact_kernel<<<512, 256, 0, stream>>>(cntb, rowtmp, rowlist, cnt);
    aux_kernel<<<2304 + 16384, 256, 0, stream>>>(W1, W1T, W2, W2T, gates, out);
    expert_kernel<<<(BROWS / BM) * EEXP, 256, 0, stream>>>(
        xbf, gates, W1T, b1, W2T, b2, cnt, rowlist, out);
}

// Round 2
// 185.146 us; speedup vs baseline: 1.0600x; 1.0600x over previous
//
#include <hip/hip_runtime.h>
#include <stdint.h>

#define BROWS 16384
#define DDIM  512
#define EEXP  16
#define HDIM  256
#define LDIM  64
#define BM    64

typedef __bf16  bf16x8  __attribute__((ext_vector_type(8)));
typedef float   floatx4 __attribute__((ext_vector_type(4)));
typedef ushort  ushort8 __attribute__((ext_vector_type(8)));
typedef unsigned int u32;

__device__ __forceinline__ ushort f2bf(float f) {
    uint32_t u = __builtin_bit_cast(uint32_t, f);
    u += 0x7fffu + ((u >> 16) & 1u);   // RNE
    return (ushort)(u >> 16);
}

// tanh(x) = 1 - 2/(exp2(2x*log2e)+1); saturates correctly, rel err ~1e-6.
__device__ __forceinline__ float fast_tanh(float x) {
    float e = __builtin_amdgcn_exp2f(x * 2.8853900817779268f);
    return 1.0f - 2.0f * __builtin_amdgcn_rcpf(e + 1.0f);
}

__device__ __forceinline__ void gl_lds16(const void* g, void* l) {
    __builtin_amdgcn_global_load_lds(
        (const __attribute__((address_space(1))) u32*)g,
        (__attribute__((address_space(3))) u32*)l, 16, 0, 0);
}

// ---------------------------------------------------------------------------
// Gating (f32, math unchanged) + fused x f32->bf16 swizzled cvt
// + per-(expert, gating-block) row slots (NO global atomics -> sortable).
// 32 rows/block; thread = (rg 0..15, og 0..15): 2 rows x (wg,wn) each.
// ---------------------------------------------------------------------------
__global__ __launch_bounds__(256) void gating_kernel(
    const float* __restrict__ x,      // [B][D]
    const float* __restrict__ noise,  // [B][E]
    const float* __restrict__ wg,     // [D][E]
    const float* __restrict__ wn,     // [D][E]
    float* __restrict__ gates,        // [B][E]
    ushort* __restrict__ xbf,         // [B][D] bf16 swizzled
    u32* __restrict__ cntb,           // [E][512] per-block counts
    u32* __restrict__ rowtmp)         // [E][512*32] slotted rows
{
    __shared__ __align__(16) float xs[32 * 132];    // 16.5 KB
    __shared__ __align__(16) float wTg[16 * 132];   // 8.25 KB
    __shared__ __align__(16) float wTn[16 * 132];   // 8.25 KB
    __shared__ u32 lcnt[16];
    __shared__ ushort lrows[16 * 32];

    const int t    = threadIdx.x;
    const int blk  = blockIdx.x;
    const int row0 = blk * 32;
    const int og   = t & 15, rg = t >> 4;

    if (t < 16) lcnt[t] = 0;

    floatx4 accg4[2] = {}, accn4[2] = {};

    for (int ch = 0; ch < 4; ++ch) {
        const int k0 = ch * 128;
        __syncthreads();
        {   // stage xs[32][128] + fused bf16 swizzled writeback
            int r = t >> 3, c = (t & 7) * 16;
            const float* src = &x[(size_t)(row0 + r) * DDIM + k0 + c];
            float4 f[4];
            #pragma unroll
            for (int i = 0; i < 4; ++i)
                f[i] = reinterpret_cast<const float4*>(src)[i];
            float* dst = &xs[r * 132 + c];
            #pragma unroll
            for (int i = 0; i < 4; ++i)
                reinterpret_cast<float4*>(dst)[i] = f[i];

            const int row = row0 + r;
            const int sw  = r & 7;
            #pragma unroll
            for (int i = 0; i < 2; ++i) {
                int cb = k0 + c + i * 8;
                int kb = cb >> 6;
                int g  = (cb >> 3) & 7;
                int gp = g ^ sw;
                float4 a = f[i * 2], b = f[i * 2 + 1];
                ushort8 t8;
                t8[0]=f2bf(a.x); t8[1]=f2bf(a.y); t8[2]=f2bf(a.z); t8[3]=f2bf(a.w);
                t8[4]=f2bf(b.x); t8[5]=f2bf(b.y); t8[6]=f2bf(b.z); t8[7]=f2bf(b.w);
                *reinterpret_cast<ushort8*>(&xbf[(size_t)row * DDIM + kb * 64 + gp * 8]) = t8;
            }
        }
        {   // stage wTg/wTn transposed (pad 132 -> conflict-free reads)
            int d = t >> 1, e0 = (t & 1) * 8;
            float4 a0 = *reinterpret_cast<const float4*>(&wg[(size_t)(k0 + d) * EEXP + e0]);
            float4 a1 = *reinterpret_cast<const float4*>(&wg[(size_t)(k0 + d) * EEXP + e0 + 4]);
            float4 b0 = *reinterpret_cast<const float4*>(&wn[(size_t)(k0 + d) * EEXP + e0]);
            float4 b1 = *reinterpret_cast<const float4*>(&wn[(size_t)(k0 + d) * EEXP + e0 + 4]);
            wTg[(e0+0)*132+d]=a0.x; wTg[(e0+1)*132+d]=a0.y; wTg[(e0+2)*132+d]=a0.z; wTg[(e0+3)*132+d]=a0.w;
            wTg[(e0+4)*132+d]=a1.x; wTg[(e0+5)*132+d]=a1.y; wTg[(e0+6)*132+d]=a1.z; wTg[(e0+7)*132+d]=a1.w;
            wTn[(e0+0)*132+d]=b0.x; wTn[(e0+1)*132+d]=b0.y; wTn[(e0+2)*132+d]=b0.z; wTn[(e0+3)*132+d]=b0.w;
            wTn[(e0+4)*132+d]=b1.x; wTn[(e0+5)*132+d]=b1.y; wTn[(e0+6)*132+d]=b1.z; wTn[(e0+7)*132+d]=b1.w;
        }
        __syncthreads();

        #pragma unroll 8
        for (int d4 = 0; d4 < 32; ++d4) {
            floatx4 wgv = *reinterpret_cast<const floatx4*>(&wTg[og * 132 + d4 * 4]);
            floatx4 wnv = *reinterpret_cast<const floatx4*>(&wTn[og * 132 + d4 * 4]);
            #pragma unroll
            for (int rr = 0; rr < 2; ++rr) {
                floatx4 xv = *reinterpret_cast<const floatx4*>(&xs[(rg * 2 + rr) * 132 + d4 * 4]);
                accg4[rr] += xv * wgv;
                accn4[rr] += xv * wnv;
            }
        }
    }

    #pragma unroll
    for (int rr = 0; rr < 2; ++rr) {
        const int row = row0 + rg * 2 + rr;
        float accg = accg4[rr][0] + accg4[rr][1] + accg4[rr][2] + accg4[rr][3];
        float accn = accn4[rr][0] + accn4[rr][1] + accn4[rr][2] + accn4[rr][3];

        // keep libcall-precision softplus: gate threshold flips are the risk
        float sp = fmaxf(accn, 0.f) + log1pf(expf(-fabsf(accn)));
        float stddev = sp + 0.01f;
        float nz = noise[(size_t)row * EEXP + og];
        float z = accg + nz * stddev;

        float m = z;
        #pragma unroll
        for (int mask = 8; mask >= 1; mask >>= 1)
            m = fmaxf(m, __shfl_xor(m, mask, 16));
        float ez = expf(z - m);
        float s = ez;
        #pragma unroll
        for (int mask = 8; mask >= 1; mask >>= 1)
            s += __shfl_xor(s, mask, 16);
        float logit = ez / s;

        float lsum = logit;
        #pragma unroll
        for (int mask = 8; mask >= 1; mask >>= 1)
            lsum += __shfl_xor(lsum, mask, 16);
        float mean = lsum * (1.0f / 16.0f) - 1e-8f;

        float gate = (logit >= mean) ? logit : 0.0f;
        float denom = gate;
        #pragma unroll
        for (int mask = 8; mask >= 1; mask >>= 1)
            denom += __shfl_xor(denom, mask, 16);

        gates[(size_t)row * EEXP + og] = gate / denom;

        if (gate > 0.0f) {
            u32 p = atomicAdd(&lcnt[og], 1u);
            lrows[og * 32 + p] = (ushort)(rg * 2 + rr);
        }
    }

    __syncthreads();
    if (t < 16) cntb[t * 512 + blk] = lcnt[t];
    for (int i = t; i < 16 * 32; i += 256) {
        int e = i >> 5, j = i & 31;
        if ((u32)j < lcnt[e])
            rowtmp[(size_t)e * 16384 + blk * 32 + j] = row0 + lrows[e * 32 + j];
    }
}

// ---------------------------------------------------------------------------
// Compaction: block b (512 total) computes bases[e][b] = sum cntb[e][0..b)
// redundantly (wave-parallel, L2-hot), then copies its <=32 rows per expert
// into the globally SORTED rowlist. Block 511 also writes cnt[e].
// ---------------------------------------------------------------------------
__global__ __launch_bounds__(256) void compact_kernel(
    const u32* __restrict__ cntb,     // [E][512]
    const u32* __restrict__ rowtmp,   // [E][512*32]
    u32* __restrict__ rowlist,        // [E][B] sorted
    u32* __restrict__ cnt)            // [E]
{
    __shared__ u32 base_s[16];
    const int b    = blockIdx.x;
    const int lane = threadIdx.x & 63;
    const int wave = threadIdx.x >> 6;

    for (int e = wave; e < 16; e += 4) {
        u32 s = 0;
        for (int i = lane; i < b; i += 64) s += cntb[e * 512 + i];
        #pragma unroll
        for (int off = 32; off; off >>= 1) s += __shfl_down(s, off, 64);
        if (lane == 0) {
            base_s[e] = s;
            if (b == 511) cnt[e] = s + cntb[e * 512 + 511];
        }
    }
    __syncthreads();

    const int t = threadIdx.x;
    for (int i = t; i < 512; i += 256) {
        int e = i >> 5, j = i & 31;
        if ((u32)j < cntb[e * 512 + b])
            rowlist[(size_t)e * BROWS + base_s[e] + j] =
                rowtmp[(size_t)e * 16384 + b * 32 + j];
    }
}

// ---------------------------------------------------------------------------
// Merged aux kernel: W1/W2 transpose+cvt (blocks 0..2303; W1T swizzled for
// conflict-free LDS reads in expert kernel) and zero-fill of inactive out
// slots (blocks 2304..18687). Runs after gating (needs gates).
// ---------------------------------------------------------------------------
__global__ __launch_bounds__(256) void aux_kernel(
    const float* __restrict__ W1, ushort* __restrict__ W1T,
    const float* __restrict__ W2, ushort* __restrict__ W2T,
    const float* __restrict__ gates, float* __restrict__ out)
{
    int b = blockIdx.x;
    if (b >= 2304) {   // zero-fill: one float4 per thread
        int i = (b - 2304) * 256 + threadIdx.x;
        int slot = i >> 4;
        if (gates[slot] == 0.0f) {
            float4 z = {0.f, 0.f, 0.f, 0.f};
            reinterpret_cast<float4*>(out)[i] = z;
        }
        return;
    }
    __shared__ float tile[32][33];
    const float* src; ushort* dst; int R, C, c0, r0, swz, ei;
    if (b < 2048) {
        ei = b >> 7; int rem = b & 127;
        c0 = (rem & 7) * 32; r0 = (rem >> 3) * 32;
        R = DDIM; C = HDIM; swz = 1;
        src = W1; dst = W1T;
    } else {
        b -= 2048;
        ei = b >> 4; int rem = b & 15;
        c0 = (rem & 1) * 32; r0 = (rem >> 1) * 32;
        R = HDIM; C = LDIM; swz = 0;
        src = W2; dst = W2T;
    }
    const int tx = threadIdx.x & 31, ty = threadIdx.x >> 5;
    const float* s = src + (size_t)ei * R * C;
    ushort* d = dst + (size_t)ei * R * C;

    #pragma unroll
    for (int i = 0; i < 4; ++i) {
        int rr = ty + i * 8;
        tile[rr][tx] = s[(size_t)(r0 + rr) * C + c0 + tx];
    }
    __syncthreads();
    #pragma unroll
    for (int i = 0; i < 4; ++i) {
        int cc = ty + i * 8;
        int h = c0 + cc;
        int col = r0 + tx;
        int col2 = col;
        if (swz) {
            int g = (col >> 3) & 7;
            col2 = (col & ~63) | ((g ^ (h & 7)) << 3) | (col & 7);
        }
        d[(size_t)h * R + col2] = f2bf(tile[tx][cc]);
    }
}

// ---------------------------------------------------------------------------
// Sparse expert MLP, BM=64. T3/T4 pipelined K-loop:
//   - A (8 KB, gathered rows) AND B (32 KB, W1T) double-buffered: 80 KB LDS
//     -> 2 blocks/CU. Tile kb+2 staged (fire-and-forget global_load_lds) at
//     the BOTTOM of iteration kb; at the top of iteration kb we wait only
//     s_waitcnt vmcnt(10) (the 10 newest loads = tile kb+1 stay IN FLIGHT
//     across both barriers) -> each tile's loads get a full compute phase
//     to land instead of a serial stage->drain->compute chain.
//   - B LDS slices are wave-private (each wave MFMAs only rows it staged);
//     only A is cross-wave -> per-wave vmcnt + barrier is sufficient.
//   - T5: setprio(1) around the MFMA cluster (2 blocks/CU gives the
//     scheduler role-diverse waves to arbitrate).
// h (32 KB) reuses [0,32K) after the K-loop's final barrier.
// ---------------------------------------------------------------------------
__global__ __launch_bounds__(256, 2) void expert_kernel(
    const ushort* __restrict__ xbf,    // [B][D] bf16, swizzled
    const float*  __restrict__ gates,  // [B][E]
    const ushort* __restrict__ W1T,    // [E][H][D] bf16, swizzled
    const float*  __restrict__ b1,     // [E][H]
    const ushort* __restrict__ W2T,    // [E][L][H] bf16, linear
    const float*  __restrict__ b2,     // [E][L]
    const u32*    __restrict__ cnt,    // [E]
    const u32*    __restrict__ rowlist,// [E][B] sorted
    float* __restrict__ out)           // [B][E][L]
{
    // A0 [0,4096), A1 [4096,8192), B0 [8192,24576), B1 [24576,40960) ushorts
    __shared__ __align__(16) ushort lds[40960];  // 80 KB

    const int bx = blockIdx.x;
    const int e  = bx & 15;
    const int t  = bx >> 4;

    const int count = (int)cnt[e];
    if (t * BM >= count) return;
    const int nrt = min(BM, count - t * BM);
    const u32* rl = rowlist + (size_t)e * BROWS + t * BM;

    const int tid  = threadIdx.x;
    const int lane = tid & 63;
    const int wave = tid >> 6;

    const int lr = lane & 15;
    const int q  = lane >> 4;
    const int kq = q * 8;
    const int rq = q * 4;
    const int la = lane >> 3, lb = lane & 7;  // staging lane split

    const char* xg = (const char*)xbf;
    const char* w1 = (const char*)W1T + (size_t)e * HDIM * 1024;

    // Per-lane gathered A-row bases + swizzle re-key terms
    size_t abase[2]; int sxr[2];
    #pragma unroll
    for (int p = 0; p < 2; ++p) {
        int r  = wave * 16 + p * 8 + la;
        int rc = min(r, nrt - 1);
        u32 ri = rl[rc];
        abase[p] = (size_t)ri * 1024;
        sxr[p]   = (la ^ (int)(ri & 7)) << 4;
    }

    auto stage = [&](int tl) {
        const int koff = tl * 128;                 // byte offset within 1024-B row
        const int da = (tl & 1) << 12;             // A: 0 / 4096
        const int db = 8192 + ((tl & 1) << 14);    // B: 8192 / 24576
        #pragma unroll
        for (int p = 0; p < 2; ++p) {
            int c = wave * 2 + p;
            gl_lds16(xg + abase[p] + koff + ((lb << 4) ^ sxr[p]), &lds[da + c * 512]);
        }
        #pragma unroll
        for (int p = 0; p < 8; ++p) {
            int c = wave * 8 + p;
            gl_lds16(w1 + (size_t)(c * 8 + la) * 1024 + koff + (lb << 4),
                     &lds[db + c * 512]);
        }
    };

    floatx4 acc[4][4] = {};

    stage(0);   // 10 loads/thread
    stage(1);   // 10 more -> 20 outstanding

    #pragma unroll
    for (int kb = 0; kb < 8; ++kb) {
        // Drain tile kb's loads (leave tile kb+1's 10 in flight), then sync.
        if (kb < 7) { asm volatile("s_waitcnt vmcnt(10)" ::: "memory"); }
        else        { asm volatile("s_waitcnt vmcnt(0)"  ::: "memory"); }
        __builtin_amdgcn_s_barrier();
        __builtin_amdgcn_sched_barrier(0);

        const int cA = (kb & 1) << 12;
        const int cB = 8192 + ((kb & 1) << 14);
        #pragma unroll
        for (int s = 0; s < 2; ++s) {
            const int g = s * 4 + q;
            bf16x8 af[4], bfr[4];
            #pragma unroll
            for (int i = 0; i < 4; ++i) {
                int r = i * 16 + lr;
                af[i] = *reinterpret_cast<const bf16x8*>(
                    &lds[cA + r * 64 + ((g ^ (r & 7)) << 3)]);
            }
            #pragma unroll
            for (int j = 0; j < 4; ++j) {
                int r = wave * 64 + j * 16 + lr;
                bfr[j] = *reinterpret_cast<const bf16x8*>(
                    &lds[cB + r * 64 + ((g ^ (r & 7)) << 3)]);
            }
            __builtin_amdgcn_s_setprio(1);
            #pragma unroll
            for (int i = 0; i < 4; ++i)
                #pragma unroll
                for (int j = 0; j < 4; ++j)
                    acc[i][j] = __builtin_amdgcn_mfma_f32_16x16x32_bf16(
                        af[i], bfr[j], acc[i][j], 0, 0, 0);
            __builtin_amdgcn_s_setprio(0);
        }
        // All waves done reading buf[kb&1] before tile kb+2 overwrites it.
        asm volatile("s_waitcnt lgkmcnt(0)" ::: "memory");
        __builtin_amdgcn_s_barrier();
        __builtin_amdgcn_sched_barrier(0);
        if (kb < 6) stage(kb + 2);
    }

    // h = fast_tanh(acc + b1) -> bf16, swizzled [64][256] at lds[0..32K)
    float b1v[4];
    #pragma unroll
    for (int j = 0; j < 4; ++j)
        b1v[j] = b1[e * HDIM + wave * 64 + j * 16 + lr];

    #pragma unroll
    for (int i = 0; i < 4; ++i)
        #pragma unroll
        for (int j = 0; j < 4; ++j) {
            int c = wave * 64 + j * 16 + lr;
            int gg = c >> 3;
            #pragma unroll
            for (int rr = 0; rr < 4; ++rr) {
                int r = i * 16 + rq + rr;
                float v = fast_tanh(acc[i][j][rr] + b1v[j]);
                lds[r * 256 + (((gg & 24) | ((gg & 7) ^ (r & 7))) << 3) + (c & 7)] = f2bf(v);
            }
        }
    __syncthreads();

    // Phase B: y[64][64]; wave owns rows [wave*16,+16); W2 frags from global
    const ushort* w2 = W2T + (size_t)e * LDIM * HDIM;
    floatx4 acc2[4] = {};
    #pragma unroll
    for (int s = 0; s < 8; ++s) {
        int r = wave * 16 + lr;
        int g = s * 4 + q;
        bf16x8 af = *reinterpret_cast<const bf16x8*>(
            &lds[r * 256 + (((g & 24) | ((g & 7) ^ (r & 7))) << 3)]);
        #pragma unroll
        for (int j = 0; j < 4; ++j) {
            bf16x8 bfr = *reinterpret_cast<const bf16x8*>(
                &w2[(size_t)(j * 16 + lr) * HDIM + s * 32 + kq]);
            acc2[j] = __builtin_amdgcn_mfma_f32_16x16x32_bf16(af, bfr, acc2[j], 0, 0, 0);
        }
    }

    float b2v[4];
    #pragma unroll
    for (int j = 0; j < 4; ++j)
        b2v[j] = b2[e * LDIM + j * 16 + lr];

    #pragma unroll
    for (int rr = 0; rr < 4; ++rr) {
        int r  = wave * 16 + rq + rr;
        int rc = min(r, nrt - 1);
        u32 ri = rl[rc];
        float gsc = gates[(size_t)ri * EEXP + e];
        if (r < nrt) {
            #pragma unroll
            for (int j = 0; j < 4; ++j)
                out[(size_t)ri * (EEXP * LDIM) + e * LDIM + j * 16 + lr] =
                    (acc2[j][rr] + b2v[j]) * gsc;
        }
    }
}

// ---------------------------------------------------------------------------
extern "C" void kernel_launch(void* const* d_in, const int* in_sizes, int n_in,
                              void* d_out, int out_size, void* d_ws, size_t ws_size,
                              hipStream_t stream) {
    (void)in_sizes; (void)n_in; (void)out_size; (void)ws_size;
    const float* x     = (const float*)d_in[0];
    const float* noise = (const float*)d_in[1];
    const float* wg    = (const float*)d_in[2];
    const float* wn    = (const float*)d_in[3];
    const float* W1    = (const float*)d_in[4];
    const float* b1    = (const float*)d_in[5];
    const float* W2    = (const float*)d_in[6];
    const float* b2    = (const float*)d_in[7];
    float* out = (float*)d_out;

    char* ws = (char*)d_ws;
    float*  gates   = (float*)ws;                          // 1 MiB
    ushort* W1T     = (ushort*)(ws + (1 << 20));           // 4 MiB
    ushort* W2T     = (ushort*)(ws + (5 << 20));           // 0.5 MiB
    ushort* xbf     = (ushort*)(ws + (6 << 20));           // 16 MiB
    u32*    cntb    = (u32*)(ws + (22 << 20));             // 32 KiB
    u32*    cnt     = (u32*)(ws + (22 << 20) + (32 << 10));// 64 B
    u32*    rowtmp  = (u32*)(ws + (23 << 20));             // 1 MiB
    u32*    rowlist = (u32*)(ws + (24 << 20));             // 1 MiB

    gating_kernel<<<BROWS / 32, 256, 0, stream>>>(x, noise, wg, wn, gates, xbf, cntb, rowtmp);
    compact_kernel<<<512, 256, 0, stream>>>(cntb, rowtmp, rowlist, cnt);
    aux_kernel<<<2304 + 16384, 256, 0, stream>>>(W1, W1T, W2, W2T, gates, out);
    expert_kernel<<<(BROWS / BM) * EEXP, 256, 0, stream>>>(
        xbf, gates, W1T, b1, W2T, b2, cnt, rowlist, out);
}

// Round 3
// 177.223 us; speedup vs baseline: 1.1074x; 1.0447x over previous
//
#include <hip/hip_runtime.h>
#include <stdint.h>

#define BROWS 16384
#define DDIM  512
#define EEXP  16
#define HDIM  256
#define LDIM  64
#define BM    64

typedef __bf16  bf16x8  __attribute__((ext_vector_type(8)));
typedef float   floatx4 __attribute__((ext_vector_type(4)));
typedef ushort  ushort8 __attribute__((ext_vector_type(8)));
typedef unsigned int u32;

__device__ __forceinline__ ushort f2bf(float f) {
    uint32_t u = __builtin_bit_cast(uint32_t, f);
    u += 0x7fffu + ((u >> 16) & 1u);   // RNE
    return (ushort)(u >> 16);
}

// tanh(x) = 1 - 2/(exp2(2x*log2e)+1); saturates correctly, rel err ~1e-6.
__device__ __forceinline__ float fast_tanh(float x) {
    float e = __builtin_amdgcn_exp2f(x * 2.8853900817779268f);
    return 1.0f - 2.0f * __builtin_amdgcn_rcpf(e + 1.0f);
}

__device__ __forceinline__ void gl_lds16(const void* g, void* l) {
    __builtin_amdgcn_global_load_lds(
        (const __attribute__((address_space(1))) u32*)g,
        (__attribute__((address_space(3))) u32*)l, 16, 0, 0);
}

// ---------------------------------------------------------------------------
// MERGED kernel. Blocks 0..511: gating (f32 math unchanged) + fused x->bf16
// swizzled cvt + INLINE zero-fill of inactive out slots + direct atomic
// rowlist build (compact_kernel removed; within-expert order is irrelevant:
// each gathered row is a 1KB block read exactly once per expert).
// Blocks 512..2815: W1/W2 transpose+cvt (independent of gating -> overlaps
// in the same dispatch instead of serializing as a later kernel).
// ---------------------------------------------------------------------------
__global__ __launch_bounds__(256) void gate_aux_kernel(
    const float* __restrict__ x,      // [B][D]
    const float* __restrict__ noise,  // [B][E]
    const float* __restrict__ wg,     // [D][E]
    const float* __restrict__ wn,     // [D][E]
    const float* __restrict__ W1,     // [E][D][H]
    const float* __restrict__ W2,     // [E][H][L]
    float* __restrict__ gates,        // [B][E]
    ushort* __restrict__ xbf,         // [B][D] bf16 swizzled
    ushort* __restrict__ W1T,         // [E][H][D] bf16 swizzled
    ushort* __restrict__ W2T,         // [E][L][H] bf16 linear
    u32* __restrict__ cnt,            // [E] (pre-zeroed)
    u32* __restrict__ rowlist,        // [E][B] unsorted-compact
    float* __restrict__ out)          // [B][E][L]
{
    if (blockIdx.x >= 512) {
        // ---- transpose path ----
        __shared__ float tile[32][33];
        int b = blockIdx.x - 512;
        const float* src; ushort* dst; int R, C, c0, r0, swz, ei;
        if (b < 2048) {
            ei = b >> 7; int rem = b & 127;
            c0 = (rem & 7) * 32; r0 = (rem >> 3) * 32;
            R = DDIM; C = HDIM; swz = 1;
            src = W1; dst = W1T;
        } else {
            b -= 2048;
            ei = b >> 4; int rem = b & 15;
            c0 = (rem & 1) * 32; r0 = (rem >> 1) * 32;
            R = HDIM; C = LDIM; swz = 0;
            src = W2; dst = W2T;
        }
        const int tx = threadIdx.x & 31, ty = threadIdx.x >> 5;
        const float* s = src + (size_t)ei * R * C;
        ushort* d = dst + (size_t)ei * R * C;

        #pragma unroll
        for (int i = 0; i < 4; ++i) {
            int rr = ty + i * 8;
            tile[rr][tx] = s[(size_t)(r0 + rr) * C + c0 + tx];
        }
        __syncthreads();
        #pragma unroll
        for (int i = 0; i < 4; ++i) {
            int cc = ty + i * 8;
            int h = c0 + cc;
            int col = r0 + tx;
            int col2 = col;
            if (swz) {
                int g = (col >> 3) & 7;
                col2 = (col & ~63) | ((g ^ (h & 7)) << 3) | (col & 7);
            }
            d[(size_t)h * R + col2] = f2bf(tile[tx][cc]);
        }
        return;
    }

    // ---- gating path ----
    __shared__ __align__(16) float xs[32 * 132];    // 16.5 KB
    __shared__ __align__(16) float wTg[16 * 132];   // 8.25 KB
    __shared__ __align__(16) float wTn[16 * 132];   // 8.25 KB
    __shared__ u32 lcnt[16];
    __shared__ u32 lbase[16];
    __shared__ ushort lrows[16 * 32];

    const int t    = threadIdx.x;
    const int blk  = blockIdx.x;
    const int row0 = blk * 32;
    const int og   = t & 15, rg = t >> 4;

    if (t < 16) lcnt[t] = 0;

    floatx4 accg4[2] = {}, accn4[2] = {};

    for (int ch = 0; ch < 4; ++ch) {
        const int k0 = ch * 128;
        __syncthreads();
        {   // stage xs[32][128] + fused bf16 swizzled writeback
            int r = t >> 3, c = (t & 7) * 16;
            const float* src = &x[(size_t)(row0 + r) * DDIM + k0 + c];
            float4 f[4];
            #pragma unroll
            for (int i = 0; i < 4; ++i)
                f[i] = reinterpret_cast<const float4*>(src)[i];
            float* dst = &xs[r * 132 + c];
            #pragma unroll
            for (int i = 0; i < 4; ++i)
                reinterpret_cast<float4*>(dst)[i] = f[i];

            const int row = row0 + r;
            const int sw  = r & 7;
            #pragma unroll
            for (int i = 0; i < 2; ++i) {
                int cb = k0 + c + i * 8;
                int kb = cb >> 6;
                int g  = (cb >> 3) & 7;
                int gp = g ^ sw;
                float4 a = f[i * 2], b = f[i * 2 + 1];
                ushort8 t8;
                t8[0]=f2bf(a.x); t8[1]=f2bf(a.y); t8[2]=f2bf(a.z); t8[3]=f2bf(a.w);
                t8[4]=f2bf(b.x); t8[5]=f2bf(b.y); t8[6]=f2bf(b.z); t8[7]=f2bf(b.w);
                *reinterpret_cast<ushort8*>(&xbf[(size_t)row * DDIM + kb * 64 + gp * 8]) = t8;
            }
        }
        {   // stage wTg/wTn transposed (pad 132 -> conflict-free reads)
            int d = t >> 1, e0 = (t & 1) * 8;
            float4 a0 = *reinterpret_cast<const float4*>(&wg[(size_t)(k0 + d) * EEXP + e0]);
            float4 a1 = *reinterpret_cast<const float4*>(&wg[(size_t)(k0 + d) * EEXP + e0 + 4]);
            float4 b0 = *reinterpret_cast<const float4*>(&wn[(size_t)(k0 + d) * EEXP + e0]);
            float4 b1 = *reinterpret_cast<const float4*>(&wn[(size_t)(k0 + d) * EEXP + e0 + 4]);
            wTg[(e0+0)*132+d]=a0.x; wTg[(e0+1)*132+d]=a0.y; wTg[(e0+2)*132+d]=a0.z; wTg[(e0+3)*132+d]=a0.w;
            wTg[(e0+4)*132+d]=a1.x; wTg[(e0+5)*132+d]=a1.y; wTg[(e0+6)*132+d]=a1.z; wTg[(e0+7)*132+d]=a1.w;
            wTn[(e0+0)*132+d]=b0.x; wTn[(e0+1)*132+d]=b0.y; wTn[(e0+2)*132+d]=b0.z; wTn[(e0+3)*132+d]=b0.w;
            wTn[(e0+4)*132+d]=b1.x; wTn[(e0+5)*132+d]=b1.y; wTn[(e0+6)*132+d]=b1.z; wTn[(e0+7)*132+d]=b1.w;
        }
        __syncthreads();

        #pragma unroll 8
        for (int d4 = 0; d4 < 32; ++d4) {
            floatx4 wgv = *reinterpret_cast<const floatx4*>(&wTg[og * 132 + d4 * 4]);
            floatx4 wnv = *reinterpret_cast<const floatx4*>(&wTn[og * 132 + d4 * 4]);
            #pragma unroll
            for (int rr = 0; rr < 2; ++rr) {
                floatx4 xv = *reinterpret_cast<const floatx4*>(&xs[(rg * 2 + rr) * 132 + d4 * 4]);
                accg4[rr] += xv * wgv;
                accn4[rr] += xv * wnv;
            }
        }
    }

    #pragma unroll
    for (int rr = 0; rr < 2; ++rr) {
        const int row = row0 + rg * 2 + rr;
        float accg = accg4[rr][0] + accg4[rr][1] + accg4[rr][2] + accg4[rr][3];
        float accn = accn4[rr][0] + accn4[rr][1] + accn4[rr][2] + accn4[rr][3];

        // keep libcall-precision softplus: gate threshold flips are the risk
        float sp = fmaxf(accn, 0.f) + log1pf(expf(-fabsf(accn)));
        float stddev = sp + 0.01f;
        float nz = noise[(size_t)row * EEXP + og];
        float z = accg + nz * stddev;

        float m = z;
        #pragma unroll
        for (int mask = 8; mask >= 1; mask >>= 1)
            m = fmaxf(m, __shfl_xor(m, mask, 16));
        float ez = expf(z - m);
        float s = ez;
        #pragma unroll
        for (int mask = 8; mask >= 1; mask >>= 1)
            s += __shfl_xor(s, mask, 16);
        float logit = ez / s;

        float lsum = logit;
        #pragma unroll
        for (int mask = 8; mask >= 1; mask >>= 1)
            lsum += __shfl_xor(lsum, mask, 16);
        float mean = lsum * (1.0f / 16.0f) - 1e-8f;

        float gate = (logit >= mean) ? logit : 0.0f;
        float denom = gate;
        #pragma unroll
        for (int mask = 8; mask >= 1; mask >>= 1)
            denom += __shfl_xor(denom, mask, 16);

        gates[(size_t)row * EEXP + og] = gate / denom;

        if (gate > 0.0f) {
            u32 p = atomicAdd(&lcnt[og], 1u);
            lrows[og * 32 + p] = (ushort)(rg * 2 + rr);
        } else {
            // fused zero-fill of this inactive out slot (256 B)
            float4 zf = {0.f, 0.f, 0.f, 0.f};
            float4* o = reinterpret_cast<float4*>(
                &out[(size_t)row * (EEXP * LDIM) + og * LDIM]);
            #pragma unroll
            for (int i = 0; i < 16; ++i) o[i] = zf;
        }
    }

    __syncthreads();
    if (t < 16) lbase[t] = atomicAdd(&cnt[t], lcnt[t]);
    __syncthreads();
    for (int i = t; i < 16 * 32; i += 256) {
        int e = i >> 5, j = i & 31;
        if ((u32)j < lcnt[e])
            rowlist[(size_t)e * BROWS + lbase[e] + j] = row0 + lrows[e * 32 + j];
    }
}

// ---------------------------------------------------------------------------
// Sparse expert MLP, BM=64, 40 KB LDS -> 4 blocks/CU (round-0 proven-best
// structure). Block (e,t) processes rowlist[e][t*64 .. +64) -> L2-local
// gather (lists ~row-ordered since gating blocks finish in ~row order).
// ---------------------------------------------------------------------------
__global__ __launch_bounds__(256, 4) void expert_kernel(
    const ushort* __restrict__ xbf,    // [B][D] bf16, swizzled
    const float*  __restrict__ gates,  // [B][E]
    const ushort* __restrict__ W1T,    // [E][H][D] bf16, swizzled
    const float*  __restrict__ b1,     // [E][H]
    const ushort* __restrict__ W2T,    // [E][L][H] bf16, linear
    const float*  __restrict__ b2,     // [E][L]
    const u32*    __restrict__ cnt,    // [E]
    const u32*    __restrict__ rowlist,// [E][B]
    float* __restrict__ out)           // [B][E][L]
{
    __shared__ __align__(16) ushort lds[20480];  // A [0,8K)B, B [8K,40K)B; h [0,32K)B

    const int bx = blockIdx.x;
    const int e  = bx & 15;
    const int t  = bx >> 4;

    const int count = (int)cnt[e];
    if (t * BM >= count) return;
    const int nrt = min(BM, count - t * BM);
    const u32* rl = rowlist + (size_t)e * BROWS + t * BM;

    const int tid  = threadIdx.x;
    const int lane = tid & 63;
    const int wave = tid >> 6;

    const int lr = lane & 15;
    const int q  = lane >> 4;
    const int kq = q * 8;
    const int rq = q * 4;
    const int la = lane >> 3, lb = lane & 7;  // staging lane split

    const char* xg = (const char*)xbf;
    const char* w1 = (const char*)W1T + (size_t)e * HDIM * 1024;

    // Per-lane gathered A-row bases + swizzle re-key terms
    size_t abase[2]; int sxr[2];
    #pragma unroll
    for (int p = 0; p < 2; ++p) {
        int r  = wave * 16 + p * 8 + la;
        int rc = min(r, nrt - 1);
        u32 ri = rl[rc];
        abase[p] = (size_t)ri * 1024;
        sxr[p]   = (la ^ (int)(ri & 7)) << 4;
    }

    floatx4 acc[4][4] = {};

    for (int kb = 0; kb < 8; ++kb) {
        const int koff = kb * 128;   // byte offset within 1024-B row
        #pragma unroll
        for (int p = 0; p < 2; ++p) {   // A tile: 8 KB (gathered rows)
            int c = wave * 2 + p;
            gl_lds16(xg + abase[p] + koff + ((lb << 4) ^ sxr[p]), &lds[c * 512]);
        }
        #pragma unroll
        for (int p = 0; p < 8; ++p) {   // B tile: 32 KB (sequential W1T rows)
            int c = wave * 8 + p;
            gl_lds16(w1 + (size_t)(c * 8 + la) * 1024 + koff + (lb << 4),
                     &lds[4096 + c * 512]);
        }
        __syncthreads();

        #pragma unroll
        for (int s = 0; s < 2; ++s) {
            const int g = s * 4 + q;
            bf16x8 af[4], bfr[4];
            #pragma unroll
            for (int i = 0; i < 4; ++i) {
                int r = i * 16 + lr;
                af[i] = *reinterpret_cast<const bf16x8*>(&lds[r * 64 + ((g ^ (r & 7)) << 3)]);
            }
            #pragma unroll
            for (int j = 0; j < 4; ++j) {
                int r = wave * 64 + j * 16 + lr;
                bfr[j] = *reinterpret_cast<const bf16x8*>(&lds[4096 + r * 64 + ((g ^ (r & 7)) << 3)]);
            }
            #pragma unroll
            for (int i = 0; i < 4; ++i)
                #pragma unroll
                for (int j = 0; j < 4; ++j)
                    acc[i][j] = __builtin_amdgcn_mfma_f32_16x16x32_bf16(
                        af[i], bfr[j], acc[i][j], 0, 0, 0);
        }
        __syncthreads();
    }

    // h = fast_tanh(acc + b1) -> bf16, swizzled [64][256] at lds[0..32K)
    float b1v[4];
    #pragma unroll
    for (int j = 0; j < 4; ++j)
        b1v[j] = b1[e * HDIM + wave * 64 + j * 16 + lr];

    #pragma unroll
    for (int i = 0; i < 4; ++i)
        #pragma unroll
        for (int j = 0; j < 4; ++j) {
            int c = wave * 64 + j * 16 + lr;
            int gg = c >> 3;
            #pragma unroll
            for (int rr = 0; rr < 4; ++rr) {
                int r = i * 16 + rq + rr;
                float v = fast_tanh(acc[i][j][rr] + b1v[j]);
                lds[r * 256 + (((gg & 24) | ((gg & 7) ^ (r & 7))) << 3) + (c & 7)] = f2bf(v);
            }
        }
    __syncthreads();

    // Phase B: y[64][64]; wave owns rows [wave*16,+16); W2 frags from global
    const ushort* w2 = W2T + (size_t)e * LDIM * HDIM;
    floatx4 acc2[4] = {};
    #pragma unroll
    for (int s = 0; s < 8; ++s) {
        int r = wave * 16 + lr;
        int g = s * 4 + q;
        bf16x8 af = *reinterpret_cast<const bf16x8*>(
            &lds[r * 256 + (((g & 24) | ((g & 7) ^ (r & 7))) << 3)]);
        #pragma unroll
        for (int j = 0; j < 4; ++j) {
            bf16x8 bfr = *reinterpret_cast<const bf16x8*>(
                &w2[(size_t)(j * 16 + lr) * HDIM + s * 32 + kq]);
            acc2[j] = __builtin_amdgcn_mfma_f32_16x16x32_bf16(af, bfr, acc2[j], 0, 0, 0);
        }
    }

    float b2v[4];
    #pragma unroll
    for (int j = 0; j < 4; ++j)
        b2v[j] = b2[e * LDIM + j * 16 + lr];

    #pragma unroll
    for (int rr = 0; rr < 4; ++rr) {
        int r  = wave * 16 + rq + rr;
        int rc = min(r, nrt - 1);
        u32 ri = rl[rc];
        float gsc = gates[(size_t)ri * EEXP + e];
        if (r < nrt) {
            #pragma unroll
            for (int j = 0; j < 4; ++j)
                out[(size_t)ri * (EEXP * LDIM) + e * LDIM + j * 16 + lr] =
                    (acc2[j][rr] + b2v[j]) * gsc;
        }
    }
}

// ---------------------------------------------------------------------------
extern "C" void kernel_launch(void* const* d_in, const int* in_sizes, int n_in,
                              void* d_out, int out_size, void* d_ws, size_t ws_size,
                              hipStream_t stream) {
    (void)in_sizes; (void)n_in; (void)out_size; (void)ws_size;
    const float* x     = (const float*)d_in[0];
    const float* noise = (const float*)d_in[1];
    const float* wg    = (const float*)d_in[2];
    const float* wn    = (const float*)d_in[3];
    const float* W1    = (const float*)d_in[4];
    const float* b1    = (const float*)d_in[5];
    const float* W2    = (const float*)d_in[6];
    const float* b2    = (const float*)d_in[7];
    float* out = (float*)d_out;

    char* ws = (char*)d_ws;
    float*  gates   = (float*)ws;                          // 1 MiB
    ushort* W1T     = (ushort*)(ws + (1 << 20));           // 4 MiB
    ushort* W2T     = (ushort*)(ws + (5 << 20));           // 0.5 MiB
    ushort* xbf     = (ushort*)(ws + (6 << 20));           // 16 MiB
    u32*    cnt     = (u32*)(ws + (22 << 20));             // 64 B
    u32*    rowlist = (u32*)(ws + (24 << 20));             // 1 MiB

    hipMemsetAsync(cnt, 0, EEXP * sizeof(u32), stream);
    gate_aux_kernel<<<512 + 2304, 256, 0, stream>>>(
        x, noise, wg, wn, W1, W2, gates, xbf, W1T, W2T, cnt, rowlist, out);
    expert_kernel<<<(BROWS / BM) * EEXP, 256, 0, stream>>>(
        xbf, gates, W1T, b1, W2T, b2, cnt, rowlist, out);
}